// Round 9
// baseline (244.331 us; speedup 1.0000x reference)
//
#include <hip/hip_runtime.h>
#include <hip/hip_bf16.h>

typedef __bf16 bf16x8 __attribute__((ext_vector_type(8)));
typedef float f32x4 __attribute__((ext_vector_type(4)));
typedef unsigned short us;

__device__ __forceinline__ us f2bf(float f) {
  unsigned int u = __float_as_uint(f);
  u += 0x7fffu + ((u >> 16) & 1u);
  return (us)(u >> 16);
}

__device__ __forceinline__ float bf2f(us u) {
  return __uint_as_float(((unsigned int)u) << 16);
}

__device__ __forceinline__ unsigned int pack2(float lo, float hi) {
  __hip_bfloat162 h = __float22bfloat162_rn(float2{lo, hi});
  return *(unsigned int*)&h;
}

__device__ __forceinline__ void load_lds16(const void* g, void* l) {
  __builtin_amdgcn_global_load_lds(
      (const __attribute__((address_space(1))) unsigned int*)g,
      (__attribute__((address_space(3))) unsigned int*)l, 16, 0, 0);
}

// ---------------- elementwise f32 -> bf16 ----------------
__global__ void cvt_x(const float* __restrict__ in, us* __restrict__ out) {
  size_t i = ((size_t)blockIdx.x * 256 + threadIdx.x) * 4;
  float4 v = *(const float4*)(in + i);
  ushort4 o;
  o.x = f2bf(v.x); o.y = f2bf(v.y); o.z = f2bf(v.z); o.w = f2bf(v.w);
  *(ushort4*)(out + i) = o;
}

// ---------------- transpose f32 [R][C] -> bf16 [C][R] ----------------
__global__ void tr_w(const float* __restrict__ in, us* __restrict__ out,
                     int ldin, int ldout) {
  __shared__ float tile[32][33];
  const int c0 = blockIdx.x * 32, r0 = blockIdx.y * 32;
  const int tx = threadIdx.x, ty = threadIdx.y;
#pragma unroll
  for (int j = 0; j < 4; ++j)
    tile[ty + j * 8][tx] = in[(size_t)(r0 + ty + j * 8) * ldin + c0 + tx];
  __syncthreads();
#pragma unroll
  for (int j = 0; j < 4; ++j)
    out[(size_t)(c0 + ty + j * 8) * ldout + r0 + tx] = f2bf(tile[tx][ty + j * 8]);
}

// ---------------- V slice of QKV -> VT [b*4+kv][128][2048] ----------------
__global__ void tr_v(const us* __restrict__ QKV, us* __restrict__ VT) {
  __shared__ us tile[32][33];
  const int z = blockIdx.z, b = z >> 2, kvh = z & 3;
  const us* in = QKV + (size_t)(b * 2048) * 3072 + 2560 + kvh * 128;
  us* out = VT + (size_t)z * 128 * 2048;
  const int c0 = blockIdx.x * 32, r0 = blockIdx.y * 32;
  const int tx = threadIdx.x, ty = threadIdx.y;
#pragma unroll
  for (int j = 0; j < 4; ++j)
    tile[ty + j * 8][tx] = in[(size_t)(r0 + ty + j * 8) * 3072 + c0 + tx];
  __syncthreads();
#pragma unroll
  for (int j = 0; j < 4; ++j)
    out[(size_t)(c0 + ty + j * 8) * 2048 + r0 + tx] = tile[tx][ty + j * 8];
}

// ---------------- bf16 GEMM 256x(64*NF): one barrier per K-tile (r6 config, best measured) ----------------
template <int NF, int OUTF32>
__global__ __launch_bounds__(512, 2) void gemm256(const us* __restrict__ A,
                                                  const us* __restrict__ B,
                                                  void* __restrict__ Cv, int M, int N, int K) {
  __shared__ __attribute__((aligned(16))) us Ah[2][2][256 * 32];
  __shared__ __attribute__((aligned(16))) us Bf[2][64 * NF * 64];
  const int tid = threadIdx.x;
  const int lane = tid & 63;
  const int cl = lane & 15, rg = lane >> 4;
  const int wave = tid >> 6;
  const int wm = wave >> 2, wn = wave & 3;
  const int bm = blockIdx.y, bn = blockIdx.x;
  const int NK = K >> 6;
  const int rowA = bm * 256, rowB = bn * (64 * NF);

  f32x4 acc[8][NF] = {};

  auto stage_A = [&](int bf, int h, int kt) {
#pragma unroll
    for (int i = 0; i < 2; ++i) {
      const int L = i * 512 + tid;
      const int r = L >> 2;
      const int c = (L & 3) ^ ((r >> 1) & 3);
      load_lds16(A + (size_t)(rowA + r) * K + kt * 64 + h * 32 + c * 8,
                 &Ah[bf][h][(size_t)(i * 512 + (tid & ~63)) * 8]);
    }
  };
  auto stage_B = [&](int bf, int kt) {
#pragma unroll
    for (int i = 0; i < NF; ++i) {
      const int L = i * 512 + tid;
      const int r = L >> 3;
      const int c = (L & 7) ^ (r & 7);
      load_lds16(B + (size_t)(rowB + r) * K + kt * 64 + c * 8,
                 &Bf[bf][(size_t)(i * 512 + (tid & ~63)) * 8]);
    }
  };

  stage_B(0, 0);
  stage_A(0, 0, 0);
  stage_A(0, 1, 0);
  __syncthreads();

  int buf = 0;
#pragma unroll 1
  for (int kt = 0; kt < NK; ++kt) {
    const bool nl = (kt + 1 < NK);
    if (nl) {
      stage_B(buf ^ 1, kt + 1);
      stage_A(buf ^ 1, 0, kt + 1);
      stage_A(buf ^ 1, 1, kt + 1);
    }
    {
      bf16x8 af[8], bfr[NF];
#pragma unroll
      for (int f = 0; f < 8; ++f) {
        const int r = 128 * wm + 16 * f + cl;
        af[f] = *(const bf16x8*)(&Ah[buf][0][(r * 4 + (rg ^ ((r >> 1) & 3))) * 8]);
      }
#pragma unroll
      for (int nf = 0; nf < NF; ++nf) {
        const int r = 16 * NF * wn + 16 * nf + cl;
        bfr[nf] = *(const bf16x8*)(&Bf[buf][(r * 8 + (rg ^ (r & 7))) * 8]);
      }
      __builtin_amdgcn_s_setprio(1);
#pragma unroll
      for (int f = 0; f < 8; ++f)
#pragma unroll
        for (int nf = 0; nf < NF; ++nf)
          acc[f][nf] = __builtin_amdgcn_mfma_f32_16x16x32_bf16(af[f], bfr[nf], acc[f][nf], 0, 0, 0);
      __builtin_amdgcn_s_setprio(0);
    }
    {
      bf16x8 af[8], bfr[NF];
#pragma unroll
      for (int f = 0; f < 8; ++f) {
        const int r = 128 * wm + 16 * f + cl;
        af[f] = *(const bf16x8*)(&Ah[buf][1][(r * 4 + (rg ^ ((r >> 1) & 3))) * 8]);
      }
#pragma unroll
      for (int nf = 0; nf < NF; ++nf) {
        const int r = 16 * NF * wn + 16 * nf + cl;
        bfr[nf] = *(const bf16x8*)(&Bf[buf][(r * 8 + ((4 + rg) ^ (r & 7))) * 8]);
      }
      __builtin_amdgcn_s_setprio(1);
#pragma unroll
      for (int f = 0; f < 8; ++f)
#pragma unroll
        for (int nf = 0; nf < NF; ++nf)
          acc[f][nf] = __builtin_amdgcn_mfma_f32_16x16x32_bf16(af[f], bfr[nf], acc[f][nf], 0, 0, 0);
      __builtin_amdgcn_s_setprio(0);
    }
    __syncthreads();
    buf ^= 1;
  }

#pragma unroll
  for (int f = 0; f < 8; ++f)
#pragma unroll
    for (int nf = 0; nf < NF; ++nf)
#pragma unroll
      for (int i = 0; i < 4; ++i) {
        const int row = bm * 256 + wm * 128 + f * 16 + rg * 4 + i;
        const int col = bn * 64 * NF + wn * 16 * NF + nf * 16 + cl;
        if (OUTF32)
          ((float*)Cv)[(size_t)row * N + col] = acc[f][nf][i];
        else
          ((us*)Cv)[(size_t)row * N + col] = f2bf(acc[f][nf][i]);
      }
}

// ---- causal GQA flash attention: 32q/wave, 128-row q-tiles, k-SPLIT halves + partials ----
// grid (32 = 16 jt x 2 khalf [heavy-first], 16 h, 2 b) = 1024 blocks, 2/CU resident, 4x queue.
// half0: kt in [0, jt+1); half1: [jt+1, 2jt+2)  -- equal length, fully independent softmax.
// Emits unnormalized O (bf16) into Opart[half] and (m,l) into ML[half]; merged by merge_o.
__global__ __launch_bounds__(256, 2) void attn(const us* __restrict__ QKV,
                                               const us* __restrict__ VT,
                                               us* __restrict__ Opart,
                                               float2* __restrict__ ML) {
  __shared__ __attribute__((aligned(16))) us Ks[2][64 * 128];
  __shared__ __attribute__((aligned(16))) us VTs[2][128 * 64];
  const int T = 2048, LD = 3072;
  const int jt = 15 - (blockIdx.x & 15);
  const int half = blockIdx.x >> 4;
  const int h = blockIdx.y, b = blockIdx.z;
  const int kvh = h >> 2;
  const int tid = threadIdx.x, lane = tid & 63, wave = tid >> 6;
  const int cl = lane & 15, rg = lane >> 4;
  const bool abit = (lane & 16) != 0, bbit = (lane & 32) != 0;
  const bool ab = abit != bbit;
  const us* Kbase = QKV + (size_t)b * T * LD + 2048 + kvh * 128;
  const us* Vbase = VT + (size_t)(b * 4 + kvh) * 128 * T;

  auto stage = [&](int sb, int kt) {
    const int k0 = kt * 64;
#pragma unroll
    for (int i = 0; i < 4; ++i) {
      const int Ls = i * 256 + tid;
      const int r = Ls >> 4, s = Ls & 15, c = s ^ (r & 7);
      load_lds16(Kbase + (size_t)(k0 + r) * LD + c * 8,
                 &Ks[sb][(i * 256 + (tid & 0xC0)) * 8]);
    }
#pragma unroll
    for (int i = 0; i < 4; ++i) {
      const int Ls = i * 256 + tid;
      const int r = Ls >> 3, s = Ls & 7, c = s ^ (r & 7);
      load_lds16(Vbase + (size_t)r * T + k0 + c * 8,
                 &VTs[sb][(i * 256 + (tid & 0xC0)) * 8]);
    }
  };

  const float scale = 0.08838834764831845f;  // 1/sqrt(128)
  const int q0 = jt * 128;
  const int qb = q0 + wave * 32;
  const int kb = half ? (jt + 1) : 0;
  const int ke = half ? (2 * jt + 2) : (jt + 1);

  bf16x8 qf[2][4];
#pragma unroll
  for (int sub = 0; sub < 2; ++sub) {
    const us* Qp = QKV + (size_t)(b * T + qb + sub * 16 + cl) * LD + h * 128;
#pragma unroll
    for (int ks = 0; ks < 4; ++ks) qf[sub][ks] = *(const bf16x8*)(Qp + ks * 32 + rg * 8);
  }

  f32x4 o[2][8] = {};
  float mrun[2] = {-1e30f, -1e30f}, lrun[2] = {0.f, 0.f};
  int buf = 0;

  stage(0, kb);
  __syncthreads();

#pragma unroll 1
  for (int kt = kb; kt < ke; ++kt) {
    if (kt + 1 < ke) stage(buf ^ 1, kt + 1);

    // S^T = K * Q^T : sa[sub][n] rows k = k0+n*16+rg*4+i, col q = cl (per subtile)
    f32x4 sa[2][4] = {};
    __builtin_amdgcn_s_setprio(1);
#pragma unroll
    for (int ks = 0; ks < 4; ++ks) {
#pragma unroll
      for (int n = 0; n < 4; ++n) {
        const int row = n * 16 + cl;
        const int p = (ks * 4 + rg) ^ (row & 7);
        const bf16x8 kf = *(const bf16x8*)(&Ks[buf][row * 128 + p * 8]);
        sa[0][n] = __builtin_amdgcn_mfma_f32_16x16x32_bf16(kf, qf[0][ks], sa[0][n], 0, 0, 0);
        sa[1][n] = __builtin_amdgcn_mfma_f32_16x16x32_bf16(kf, qf[1][ks], sa[1][n], 0, 0, 0);
      }
    }
    __builtin_amdgcn_s_setprio(0);

    const int k0 = kt * 64;
    float p[2][4][4];
    unsigned int F[2][2][4];

#pragma unroll
    for (int sub = 0; sub < 2; ++sub) {
      const int qbs = qb + sub * 16;
      const int qrow = qbs + cl;
      float pmax = -1e30f;
      if (k0 + 63 > qbs) {  // diagonal tile for this subtile
#pragma unroll
        for (int n = 0; n < 4; ++n)
#pragma unroll
          for (int i = 0; i < 4; ++i) {
            const int kg = k0 + n * 16 + rg * 4 + i;
            p[sub][n][i] = (kg > qrow) ? -1e30f : sa[sub][n][i] * scale;
            pmax = fmaxf(pmax, p[sub][n][i]);
          }
      } else {
#pragma unroll
        for (int n = 0; n < 4; ++n)
#pragma unroll
          for (int i = 0; i < 4; ++i) {
            p[sub][n][i] = sa[sub][n][i] * scale;
            pmax = fmaxf(pmax, p[sub][n][i]);
          }
      }
      pmax = fmaxf(pmax, __shfl_xor(pmax, 16));
      pmax = fmaxf(pmax, __shfl_xor(pmax, 32));

      if (!__all(pmax <= mrun[sub] + 8.f)) {  // T13 defer-max
        const float mnew = fmaxf(mrun[sub], pmax);
        const float alpha = __expf(mrun[sub] - mnew);
        mrun[sub] = mnew;
        lrun[sub] *= alpha;
#pragma unroll
        for (int n2 = 0; n2 < 8; ++n2) o[sub][n2] *= alpha;
      }

      float rs = 0.f;
#pragma unroll
      for (int n = 0; n < 4; ++n)
#pragma unroll
        for (int i = 0; i < 4; ++i) {
          p[sub][n][i] = __expf(p[sub][n][i] - mrun[sub]);
          rs += p[sub][n][i];
        }
      rs += __shfl_xor(rs, 16);
      rs += __shfl_xor(rs, 32);
      lrun[sub] += rs;

      // pack P->bf16 pairs and butterfly into PV B-fragment layout
#pragma unroll
      for (int ks2 = 0; ks2 < 2; ++ks2) {
        const unsigned int pk00 = pack2(p[sub][2 * ks2][0], p[sub][2 * ks2][1]);
        const unsigned int pk01 = pack2(p[sub][2 * ks2][2], p[sub][2 * ks2][3]);
        const unsigned int pk10 = pack2(p[sub][2 * ks2 + 1][0], p[sub][2 * ks2 + 1][1]);
        const unsigned int pk11 = pack2(p[sub][2 * ks2 + 1][2], p[sub][2 * ks2 + 1][3]);
        const unsigned int s0 = bbit ? pk00 : pk10;
        const unsigned int s1 = bbit ? pk01 : pk11;
        const unsigned int r0 = (unsigned int)__shfl_xor((int)s0, 32);
        const unsigned int r1 = (unsigned int)__shfl_xor((int)s1, 32);
        const unsigned int gk0 = bbit ? pk10 : pk00;
        const unsigned int gk1 = bbit ? pk11 : pk01;
        const unsigned int t0 = ab ? gk0 : r0;
        const unsigned int t1 = ab ? gk1 : r1;
        const unsigned int u0 = (unsigned int)__shfl_xor((int)t0, 16);
        const unsigned int u1 = (unsigned int)__shfl_xor((int)t1, 16);
        const unsigned int k20 = ab ? r0 : gk0;
        const unsigned int k21 = ab ? r1 : gk1;
        F[sub][ks2][0] = abit ? u0 : k20;
        F[sub][ks2][1] = abit ? u1 : k21;
        F[sub][ks2][2] = abit ? k20 : u0;
        F[sub][ks2][3] = abit ? k21 : u1;
      }
    }

    // O^T += V^T * P ; vf shared across the two q-subtiles (2x LDS intensity)
    __builtin_amdgcn_s_setprio(1);
#pragma unroll
    for (int ks2 = 0; ks2 < 2; ++ks2) {
      uint4 f0 = make_uint4(F[0][ks2][0], F[0][ks2][1], F[0][ks2][2], F[0][ks2][3]);
      uint4 f1 = make_uint4(F[1][ks2][0], F[1][ks2][1], F[1][ks2][2], F[1][ks2][3]);
      const bf16x8 pf0 = *(const bf16x8*)&f0;
      const bf16x8 pf1 = *(const bf16x8*)&f1;
#pragma unroll
      for (int n2 = 0; n2 < 8; ++n2) {
        const int dr = n2 * 16 + cl;
        const int p2 = (ks2 * 4 + rg) ^ (dr & 7);
        const bf16x8 vf = *(const bf16x8*)(&VTs[buf][dr * 64 + p2 * 8]);
        o[0][n2] = __builtin_amdgcn_mfma_f32_16x16x32_bf16(vf, pf0, o[0][n2], 0, 0, 0);
        o[1][n2] = __builtin_amdgcn_mfma_f32_16x16x32_bf16(vf, pf1, o[1][n2], 0, 0, 0);
      }
    }
    __builtin_amdgcn_s_setprio(0);

    __syncthreads();
    buf ^= 1;
  }

  // store unnormalized partial O (bf16) + (m,l)
  us* Op = Opart + (size_t)half * 8388608;
#pragma unroll
  for (int sub = 0; sub < 2; ++sub) {
    const int qrow = qb + sub * 16 + cl;
#pragma unroll
    for (int n2 = 0; n2 < 8; ++n2) {
      ushort4 ov;
      ov.x = f2bf(o[sub][n2][0]);
      ov.y = f2bf(o[sub][n2][1]);
      ov.z = f2bf(o[sub][n2][2]);
      ov.w = f2bf(o[sub][n2][3]);
      *(ushort4*)(Op + (size_t)(b * T + qrow) * 2048 + h * 128 + n2 * 16 + rg * 4) = ov;
    }
  }
  if (lane < 16) {
#pragma unroll
    for (int sub = 0; sub < 2; ++sub) {
      const int q = qb + sub * 16 + lane;
      ML[half * 65536 + ((b * 16 + h) * 2048 + q)] = float2{mrun[sub], lrun[sub]};
    }
  }
}

// ---------------- merge the two k-half partials -> final O (bf16) ----------------
__global__ void merge_o(const us* __restrict__ Op, const float2* __restrict__ ML,
                        us* __restrict__ O) {
  const int idx = blockIdx.x * 256 + threadIdx.x;  // 1,048,576 threads
  const int row = idx >> 8;         // b*2048 + q
  const int col = (idx & 255) * 8;  // 0..2040
  const int h = col >> 7;
  const int b = row >> 11, q = row & 2047;
  const int mlrow = (b * 16 + h) * 2048 + q;
  const float2 ml0 = ML[mlrow];
  const float2 ml1 = ML[65536 + mlrow];
  const float m = fmaxf(ml0.x, ml1.x);
  const float a0 = __expf(ml0.x - m), a1 = __expf(ml1.x - m);
  const float rl = __builtin_amdgcn_rcpf(ml0.y * a0 + ml1.y * a1);
  const float s0 = a0 * rl, s1 = a1 * rl;
  const size_t base = (size_t)row * 2048 + col;
  const ushort4 x0 = *(const ushort4*)(Op + base);
  const ushort4 x1 = *(const ushort4*)(Op + base + 4);
  const ushort4 y0 = *(const ushort4*)(Op + 8388608 + base);
  const ushort4 y1 = *(const ushort4*)(Op + 8388608 + base + 4);
  ushort4 o0, o1;
  o0.x = f2bf(bf2f(x0.x) * s0 + bf2f(y0.x) * s1);
  o0.y = f2bf(bf2f(x0.y) * s0 + bf2f(y0.y) * s1);
  o0.z = f2bf(bf2f(x0.z) * s0 + bf2f(y0.z) * s1);
  o0.w = f2bf(bf2f(x0.w) * s0 + bf2f(y0.w) * s1);
  o1.x = f2bf(bf2f(x1.x) * s0 + bf2f(y1.x) * s1);
  o1.y = f2bf(bf2f(x1.y) * s0 + bf2f(y1.y) * s1);
  o1.z = f2bf(bf2f(x1.z) * s0 + bf2f(y1.z) * s1);
  o1.w = f2bf(bf2f(x1.w) * s0 + bf2f(y1.w) * s1);
  *(ushort4*)(O + base) = o0;
  *(ushort4*)(O + base + 4) = o1;
}

extern "C" void kernel_launch(void* const* d_in, const int* in_sizes, int n_in,
                              void* d_out, int out_size, void* d_ws, size_t ws_size,
                              hipStream_t stream) {
  const float* x = (const float*)d_in[0];
  const float* Wq = (const float*)d_in[1];
  const float* Wk = (const float*)d_in[2];
  const float* Wv = (const float*)d_in[3];
  const float* Wo = (const float*)d_in[4];
  float* out = (float*)d_out;

  char* ws = (char*)d_ws;
  us* xb    = (us*)(ws);                 // x bf16, later final attn O
  us* WqkvT = (us*)(ws + 16777216);      // [3072][2048]; ML reuses this region during attn
  us* WoT   = (us*)(ws + 29360128);      // [2048][2048]
  us* QKV   = (us*)(ws + 37748736);      // [4096][3072]
  us* VTb   = (us*)(ws + 62914560);      // [8][128][2048]
  float2* ML = (float2*)(ws + 16777216);
  us* Opart  = (us*)d_out;               // partial O (2 x 16.8MB bf16) in d_out, free until last gemm

  cvt_x<<<dim3(8192), dim3(256), 0, stream>>>(x, xb);
  tr_w<<<dim3(64, 64), dim3(32, 8), 0, stream>>>(Wq, WqkvT, 2048, 2048);
  tr_w<<<dim3(16, 64), dim3(32, 8), 0, stream>>>(Wk, WqkvT + (size_t)2048 * 2048, 512, 2048);
  tr_w<<<dim3(16, 64), dim3(32, 8), 0, stream>>>(Wv, WqkvT + (size_t)2560 * 2048, 512, 2048);
  tr_w<<<dim3(64, 64), dim3(32, 8), 0, stream>>>(Wo, WoT, 2048, 2048);

  gemm256<3, 0><<<dim3(16, 16), dim3(512), 0, stream>>>(xb, WqkvT, QKV, 4096, 3072, 2048);
  tr_v<<<dim3(4, 64, 8), dim3(32, 8), 0, stream>>>(QKV, VTb);
  attn<<<dim3(32, 16, 2), dim3(256), 0, stream>>>(QKV, VTb, Opart, ML);
  merge_o<<<dim3(4096), dim3(256), 0, stream>>>(Opart, ML, xb);
  gemm256<2, 1><<<dim3(16, 16), dim3(512), 0, stream>>>(xb, WoT, out, 4096, 2048, 2048);
}

// Round 10
// 190.892 us; speedup vs baseline: 1.2799x; 1.2799x over previous
//
#include <hip/hip_runtime.h>
#include <hip/hip_bf16.h>

typedef __bf16 bf16x8 __attribute__((ext_vector_type(8)));
typedef float f32x4 __attribute__((ext_vector_type(4)));
typedef unsigned short us;

__device__ __forceinline__ us f2bf(float f) {
  unsigned int u = __float_as_uint(f);
  u += 0x7fffu + ((u >> 16) & 1u);
  return (us)(u >> 16);
}

__device__ __forceinline__ unsigned int pack2(float lo, float hi) {
  __hip_bfloat162 h = __float22bfloat162_rn(float2{lo, hi});
  return *(unsigned int*)&h;
}

__device__ __forceinline__ void load_lds16(const void* g, void* l) {
  __builtin_amdgcn_global_load_lds(
      (const __attribute__((address_space(1))) unsigned int*)g,
      (__attribute__((address_space(3))) unsigned int*)l, 16, 0, 0);
}

// ---------------- elementwise f32 -> bf16 ----------------
__global__ void cvt_x(const float* __restrict__ in, us* __restrict__ out) {
  size_t i = ((size_t)blockIdx.x * 256 + threadIdx.x) * 4;
  float4 v = *(const float4*)(in + i);
  ushort4 o;
  o.x = f2bf(v.x); o.y = f2bf(v.y); o.z = f2bf(v.z); o.w = f2bf(v.w);
  *(ushort4*)(out + i) = o;
}

// ---------------- transpose f32 [R][C] -> bf16 [C][R] ----------------
__global__ void tr_w(const float* __restrict__ in, us* __restrict__ out,
                     int ldin, int ldout) {
  __shared__ float tile[32][33];
  const int c0 = blockIdx.x * 32, r0 = blockIdx.y * 32;
  const int tx = threadIdx.x, ty = threadIdx.y;
#pragma unroll
  for (int j = 0; j < 4; ++j)
    tile[ty + j * 8][tx] = in[(size_t)(r0 + ty + j * 8) * ldin + c0 + tx];
  __syncthreads();
#pragma unroll
  for (int j = 0; j < 4; ++j)
    out[(size_t)(c0 + ty + j * 8) * ldout + r0 + tx] = f2bf(tile[tx][ty + j * 8]);
}

// ---------------- V slice of QKV -> VT [b*4+kv][128][2048] ----------------
__global__ void tr_v(const us* __restrict__ QKV, us* __restrict__ VT) {
  __shared__ us tile[32][33];
  const int z = blockIdx.z, b = z >> 2, kvh = z & 3;
  const us* in = QKV + (size_t)(b * 2048) * 3072 + 2560 + kvh * 128;
  us* out = VT + (size_t)z * 128 * 2048;
  const int c0 = blockIdx.x * 32, r0 = blockIdx.y * 32;
  const int tx = threadIdx.x, ty = threadIdx.y;
#pragma unroll
  for (int j = 0; j < 4; ++j)
    tile[ty + j * 8][tx] = in[(size_t)(r0 + ty + j * 8) * 3072 + c0 + tx];
  __syncthreads();
#pragma unroll
  for (int j = 0; j < 4; ++j)
    out[(size_t)(c0 + ty + j * 8) * 2048 + r0 + tx] = tile[tx][ty + j * 8];
}

// ---------------- bf16 GEMM 256x(64*NF), 2-phase/K-tile, counted vmcnt (round-6 best) ----------------
// 512 threads = 8 waves (2M x 4N); wave tile 128 x (16*NF). BK=64 (two k-halves of 32).
// PH0 {read 8 A-frags(kk0) + NF B-frags(kk0); issue stage_B(next); barrier; lgkmcnt(0);
//   8*NF MFMA; vmcnt(NF); barrier}  PH1 {same for kk1; issue 2x stage_A(next); vmcnt(2); barrier}.
// vmcnt never drains the just-issued prefetch.
template <int NF, int OUTF32>
__global__ __launch_bounds__(512, 2) void gemm256(const us* __restrict__ A,
                                                  const us* __restrict__ B,
                                                  void* __restrict__ Cv, int M, int N, int K) {
  __shared__ __attribute__((aligned(16))) us Ah[2][2][256 * 32];
  __shared__ __attribute__((aligned(16))) us Bf[2][64 * NF * 64];
  const int tid = threadIdx.x;
  const int lane = tid & 63;
  const int cl = lane & 15, rg = lane >> 4;
  const int wave = tid >> 6;
  const int wm = wave >> 2, wn = wave & 3;
  const int bm = blockIdx.y, bn = blockIdx.x;
  const int NK = K >> 6;
  const int rowA = bm * 256, rowB = bn * (64 * NF);

  f32x4 acc[8][NF] = {};

  auto stage_A = [&](int bf, int h, int kt) {
#pragma unroll
    for (int i = 0; i < 2; ++i) {
      const int L = i * 512 + tid;
      const int r = L >> 2;
      const int c = (L & 3) ^ ((r >> 1) & 3);
      load_lds16(A + (size_t)(rowA + r) * K + kt * 64 + h * 32 + c * 8,
                 &Ah[bf][h][(size_t)(i * 512 + (tid & ~63)) * 8]);
    }
  };
  auto stage_B = [&](int bf, int kt) {
#pragma unroll
    for (int i = 0; i < NF; ++i) {
      const int L = i * 512 + tid;
      const int r = L >> 3;
      const int c = (L & 7) ^ (r & 7);
      load_lds16(B + (size_t)(rowB + r) * K + kt * 64 + c * 8,
                 &Bf[bf][(size_t)(i * 512 + (tid & ~63)) * 8]);
    }
  };

  // prologue: B(NF), A-h0(2), A-h1(2); drain B+A0, keep A1 in flight
  stage_B(0, 0);
  stage_A(0, 0, 0);
  stage_A(0, 1, 0);
  asm volatile("s_waitcnt vmcnt(2)" ::: "memory");
  __builtin_amdgcn_s_barrier();

  int buf = 0;
#pragma unroll 1
  for (int kt = 0; kt < NK; ++kt) {
    const bool nl = (kt + 1 < NK);
    bf16x8 af[8], bfr[NF];

    // ---- PH0: kk = 0 ----
#pragma unroll
    for (int f = 0; f < 8; ++f) {
      const int r = 128 * wm + 16 * f + cl;
      af[f] = *(const bf16x8*)(&Ah[buf][0][(r * 4 + (rg ^ ((r >> 1) & 3))) * 8]);
    }
#pragma unroll
    for (int nf = 0; nf < NF; ++nf) {
      const int r = 16 * NF * wn + 16 * nf + cl;
      bfr[nf] = *(const bf16x8*)(&Bf[buf][(r * 8 + (rg ^ (r & 7))) * 8]);
    }
    if (nl) stage_B(buf ^ 1, kt + 1);
    __builtin_amdgcn_s_barrier();
    asm volatile("s_waitcnt lgkmcnt(0)" ::: "memory");
    __builtin_amdgcn_s_setprio(1);
#pragma unroll
    for (int f = 0; f < 8; ++f)
#pragma unroll
      for (int nf = 0; nf < NF; ++nf)
        acc[f][nf] = __builtin_amdgcn_mfma_f32_16x16x32_bf16(af[f], bfr[nf], acc[f][nf], 0, 0, 0);
    __builtin_amdgcn_s_setprio(0);
    if (nl) {
      if constexpr (NF == 3) { asm volatile("s_waitcnt vmcnt(3)" ::: "memory"); }
      else                   { asm volatile("s_waitcnt vmcnt(2)" ::: "memory"); }
    } else {
      asm volatile("s_waitcnt vmcnt(0)" ::: "memory");
    }
    __builtin_amdgcn_s_barrier();

    // ---- PH1: kk = 1 ----
#pragma unroll
    for (int f = 0; f < 8; ++f) {
      const int r = 128 * wm + 16 * f + cl;
      af[f] = *(const bf16x8*)(&Ah[buf][1][(r * 4 + (rg ^ ((r >> 1) & 3))) * 8]);
    }
#pragma unroll
    for (int nf = 0; nf < NF; ++nf) {
      const int r = 16 * NF * wn + 16 * nf + cl;
      bfr[nf] = *(const bf16x8*)(&Bf[buf][(r * 8 + ((4 + rg) ^ (r & 7))) * 8]);
    }
    if (nl) { stage_A(buf ^ 1, 0, kt + 1); stage_A(buf ^ 1, 1, kt + 1); }
    __builtin_amdgcn_s_barrier();
    asm volatile("s_waitcnt lgkmcnt(0)" ::: "memory");
    __builtin_amdgcn_s_setprio(1);
#pragma unroll
    for (int f = 0; f < 8; ++f)
#pragma unroll
      for (int nf = 0; nf < NF; ++nf)
        acc[f][nf] = __builtin_amdgcn_mfma_f32_16x16x32_bf16(af[f], bfr[nf], acc[f][nf], 0, 0, 0);
    __builtin_amdgcn_s_setprio(0);
    if (nl) asm volatile("s_waitcnt vmcnt(2)" ::: "memory");
    __builtin_amdgcn_s_barrier();

    buf ^= 1;
  }

#pragma unroll
  for (int f = 0; f < 8; ++f)
#pragma unroll
    for (int nf = 0; nf < NF; ++nf)
#pragma unroll
      for (int i = 0; i < 4; ++i) {
        const int row = bm * 256 + wm * 128 + f * 16 + rg * 4 + i;
        const int col = bn * 64 * NF + wn * 16 * NF + nf * 16 + cl;
        if (OUTF32)
          ((float*)Cv)[(size_t)row * N + col] = acc[f][nf][i];
        else
          ((us*)Cv)[(size_t)row * N + col] = f2bf(acc[f][nf][i]);
      }
}

// ---------------- causal GQA flash attention (round-5 version: measured best, 76 us) ----------------
__global__ __launch_bounds__(256, 2) void attn(const us* __restrict__ QKV,
                                               const us* __restrict__ VT,
                                               us* __restrict__ O) {
  __shared__ __attribute__((aligned(16))) us Ks[2][64 * 128];
  __shared__ __attribute__((aligned(16))) us VTs[2][128 * 64];
  const int T = 2048, LD = 3072, D = 2048;
  const int jp = blockIdx.x, h = blockIdx.y, b = blockIdx.z;
  const int kvh = h >> 2;
  const int tid = threadIdx.x, lane = tid & 63, wave = tid >> 6;
  const int cl = lane & 15, rg = lane >> 4;
  const bool abit = (lane & 16) != 0, bbit = (lane & 32) != 0;
  const bool ab = abit != bbit;
  const us* Kbase = QKV + (size_t)b * T * LD + 2048 + kvh * 128;
  const us* Vbase = VT + (size_t)(b * 4 + kvh) * 128 * T;

  auto stage = [&](int sb, int k0) {
#pragma unroll
    for (int i = 0; i < 4; ++i) {
      const int Ls = i * 256 + tid;
      const int r = Ls >> 4, s = Ls & 15, c = s ^ (r & 7);
      load_lds16(Kbase + (size_t)(k0 + r) * LD + c * 8,
                 &Ks[sb][(i * 256 + (tid & 0xC0)) * 8]);
    }
#pragma unroll
    for (int i = 0; i < 4; ++i) {
      const int Ls = i * 256 + tid;
      const int r = Ls >> 3, s = Ls & 7, c = s ^ (r & 7);
      load_lds16(Vbase + (size_t)r * T + k0 + c * 8,
                 &VTs[sb][(i * 256 + (tid & 0xC0)) * 8]);
    }
  };

  const float scale = 0.08838834764831845f;  // 1/sqrt(128)

#pragma unroll 1
  for (int pass = 0; pass < 2; ++pass) {
    const int jt = pass ? (31 - jp) : jp;
    const int q0 = jt * 64;
    const int nkt = jt + 1;
    const int qrow = q0 + wave * 16 + cl;

    const us* Qp = QKV + (size_t)(b * T + qrow) * LD + h * 128;
    bf16x8 qf[4];
#pragma unroll
    for (int ks = 0; ks < 4; ++ks) qf[ks] = *(const bf16x8*)(Qp + ks * 32 + rg * 8);

    f32x4 o[8] = {};
    float m = -1e30f, l = 0.f;
    int buf = 0;

    stage(0, 0);
    __syncthreads();

#pragma unroll 1
    for (int kt = 0; kt < nkt; ++kt) {
      if (kt + 1 < nkt) stage(buf ^ 1, (kt + 1) * 64);

      f32x4 sa[4] = {};
      __builtin_amdgcn_s_setprio(1);
#pragma unroll
      for (int ks = 0; ks < 4; ++ks) {
#pragma unroll
        for (int n = 0; n < 4; ++n) {
          const int row = n * 16 + cl;
          const int p = (ks * 4 + rg) ^ (row & 7);
          const bf16x8 kf = *(const bf16x8*)(&Ks[buf][row * 128 + p * 8]);
          sa[n] = __builtin_amdgcn_mfma_f32_16x16x32_bf16(kf, qf[ks], sa[n], 0, 0, 0);
        }
      }
      __builtin_amdgcn_s_setprio(0);

      const int k0 = kt * 64;
      float p[4][4];
      float pmax = -1e30f;
      if (kt == jt) {
#pragma unroll
        for (int n = 0; n < 4; ++n)
#pragma unroll
          for (int i = 0; i < 4; ++i) {
            const int kg = k0 + n * 16 + rg * 4 + i;
            p[n][i] = (kg > qrow) ? -1e30f : sa[n][i] * scale;
            pmax = fmaxf(pmax, p[n][i]);
          }
      } else {
#pragma unroll
        for (int n = 0; n < 4; ++n)
#pragma unroll
          for (int i = 0; i < 4; ++i) {
            p[n][i] = sa[n][i] * scale;
            pmax = fmaxf(pmax, p[n][i]);
          }
      }
      pmax = fmaxf(pmax, __shfl_xor(pmax, 16));
      pmax = fmaxf(pmax, __shfl_xor(pmax, 32));

      if (!__all(pmax <= m + 8.f)) {  // T13 defer-max
        const float mnew = fmaxf(m, pmax);
        const float alpha = __expf(m - mnew);
        m = mnew;
        l *= alpha;
#pragma unroll
        for (int n2 = 0; n2 < 8; ++n2) o[n2] *= alpha;
      }

      float rs = 0.f;
#pragma unroll
      for (int n = 0; n < 4; ++n)
#pragma unroll
        for (int i = 0; i < 4; ++i) {
          p[n][i] = __expf(p[n][i] - m);
          rs += p[n][i];
        }
      rs += __shfl_xor(rs, 16);
      rs += __shfl_xor(rs, 32);
      l += rs;

      unsigned int F[2][4];
#pragma unroll
      for (int ks2 = 0; ks2 < 2; ++ks2) {
        const unsigned int pk00 = pack2(p[2 * ks2][0], p[2 * ks2][1]);
        const unsigned int pk01 = pack2(p[2 * ks2][2], p[2 * ks2][3]);
        const unsigned int pk10 = pack2(p[2 * ks2 + 1][0], p[2 * ks2 + 1][1]);
        const unsigned int pk11 = pack2(p[2 * ks2 + 1][2], p[2 * ks2 + 1][3]);
        const unsigned int s0 = bbit ? pk00 : pk10;
        const unsigned int s1 = bbit ? pk01 : pk11;
        const unsigned int r0 = (unsigned int)__shfl_xor((int)s0, 32);
        const unsigned int r1 = (unsigned int)__shfl_xor((int)s1, 32);
        const unsigned int gk0 = bbit ? pk10 : pk00;
        const unsigned int gk1 = bbit ? pk11 : pk01;
        const unsigned int t0 = ab ? gk0 : r0;
        const unsigned int t1 = ab ? gk1 : r1;
        const unsigned int u0 = (unsigned int)__shfl_xor((int)t0, 16);
        const unsigned int u1 = (unsigned int)__shfl_xor((int)t1, 16);
        const unsigned int k20 = ab ? r0 : gk0;
        const unsigned int k21 = ab ? r1 : gk1;
        F[ks2][0] = abit ? u0 : k20;
        F[ks2][1] = abit ? u1 : k21;
        F[ks2][2] = abit ? k20 : u0;
        F[ks2][3] = abit ? k21 : u1;
      }

      __builtin_amdgcn_s_setprio(1);
#pragma unroll
      for (int ks2 = 0; ks2 < 2; ++ks2) {
        uint4 fu = make_uint4(F[ks2][0], F[ks2][1], F[ks2][2], F[ks2][3]);
        const bf16x8 pf = *(const bf16x8*)&fu;
#pragma unroll
        for (int n2 = 0; n2 < 8; ++n2) {
          const int dr = n2 * 16 + cl;
          const int p2 = (ks2 * 4 + rg) ^ (dr & 7);
          const bf16x8 vf = *(const bf16x8*)(&VTs[buf][dr * 64 + p2 * 8]);
          o[n2] = __builtin_amdgcn_mfma_f32_16x16x32_bf16(vf, pf, o[n2], 0, 0, 0);
        }
      }
      __builtin_amdgcn_s_setprio(0);

      __syncthreads();
      buf ^= 1;
    }

    const float rl = __builtin_amdgcn_rcpf(l);
#pragma unroll
    for (int n2 = 0; n2 < 8; ++n2) {
      ushort4 ov;
      ov.x = f2bf(o[n2][0] * rl);
      ov.y = f2bf(o[n2][1] * rl);
      ov.z = f2bf(o[n2][2] * rl);
      ov.w = f2bf(o[n2][3] * rl);
      *(ushort4*)(O + (size_t)(b * T + qrow) * D + h * 128 + n2 * 16 + rg * 4) = ov;
    }
  }
}

extern "C" void kernel_launch(void* const* d_in, const int* in_sizes, int n_in,
                              void* d_out, int out_size, void* d_ws, size_t ws_size,
                              hipStream_t stream) {
  const float* x = (const float*)d_in[0];
  const float* Wq = (const float*)d_in[1];
  const float* Wk = (const float*)d_in[2];
  const float* Wv = (const float*)d_in[3];
  const float* Wo = (const float*)d_in[4];
  float* out = (float*)d_out;

  char* ws = (char*)d_ws;
  us* xb    = (us*)(ws);                 // x bf16, later attn O
  us* WqkvT = (us*)(ws + 16777216);      // [3072][2048]
  us* WoT   = (us*)(ws + 29360128);      // [2048][2048]
  us* QKV   = (us*)(ws + 37748736);      // [4096][3072]
  us* VTb   = (us*)(ws + 62914560);      // [8][128][2048]

  cvt_x<<<dim3(8192), dim3(256), 0, stream>>>(x, xb);
  tr_w<<<dim3(64, 64), dim3(32, 8), 0, stream>>>(Wq, WqkvT, 2048, 2048);
  tr_w<<<dim3(16, 64), dim3(32, 8), 0, stream>>>(Wk, WqkvT + (size_t)2048 * 2048, 512, 2048);
  tr_w<<<dim3(16, 64), dim3(32, 8), 0, stream>>>(Wv, WqkvT + (size_t)2560 * 2048, 512, 2048);
  tr_w<<<dim3(64, 64), dim3(32, 8), 0, stream>>>(Wo, WoT, 2048, 2048);

  gemm256<3, 0><<<dim3(16, 16), dim3(512), 0, stream>>>(xb, WqkvT, QKV, 4096, 3072, 2048);
  tr_v<<<dim3(4, 64, 8), dim3(32, 8), 0, stream>>>(QKV, VTb);
  attn<<<dim3(16, 16, 2), dim3(256), 0, stream>>>(QKV, VTb, xb);
  gemm256<2, 1><<<dim3(16, 16), dim3(512), 0, stream>>>(xb, WoT, out, 4096, 2048, 2048);
}

// Round 11
// 188.286 us; speedup vs baseline: 1.2977x; 1.0138x over previous
//
#include <hip/hip_runtime.h>
#include <hip/hip_bf16.h>

typedef __bf16 bf16x8 __attribute__((ext_vector_type(8)));
typedef float f32x4 __attribute__((ext_vector_type(4)));
typedef unsigned short us;

__device__ __forceinline__ us f2bf(float f) {
  unsigned int u = __float_as_uint(f);
  u += 0x7fffu + ((u >> 16) & 1u);
  return (us)(u >> 16);
}

__device__ __forceinline__ unsigned int pack2(float lo, float hi) {
  __hip_bfloat162 h = __float22bfloat162_rn(float2{lo, hi});
  return *(unsigned int*)&h;
}

__device__ __forceinline__ void load_lds16(const void* g, void* l) {
  __builtin_amdgcn_global_load_lds(
      (const __attribute__((address_space(1))) unsigned int*)g,
      (__attribute__((address_space(3))) unsigned int*)l, 16, 0, 0);
}

// ---------------- fused prep: x->bf16 + 4 weight transposes, one dispatch ----------------
// blocks [0,8192): cvt_x ; [8192,12288): Wq^T ; [12288,13312): Wk^T ;
// [13312,14336): Wv^T ; [14336,18432): Wo^T.
__global__ void prep(const float* __restrict__ x,
                     const float* __restrict__ Wq, const float* __restrict__ Wk,
                     const float* __restrict__ Wv, const float* __restrict__ Wo,
                     us* __restrict__ xb, us* __restrict__ WqkvT, us* __restrict__ WoT) {
  __shared__ float tile[32][33];
  const int blk = blockIdx.x;
  if (blk < 8192) {
    size_t i = ((size_t)blk * 256 + threadIdx.x) * 4;
    float4 v = *(const float4*)(x + i);
    ushort4 o;
    o.x = f2bf(v.x); o.y = f2bf(v.y); o.z = f2bf(v.z); o.w = f2bf(v.w);
    *(ushort4*)(xb + i) = o;
    return;
  }
  const float* in;
  us* out;
  int ldin, ldout, bx, by;
  if (blk < 12288) {
    const int u = blk - 8192;
    in = Wq; out = WqkvT; ldin = 2048; ldout = 2048; bx = u & 63; by = u >> 6;
  } else if (blk < 13312) {
    const int u = blk - 12288;
    in = Wk; out = WqkvT + (size_t)2048 * 2048; ldin = 512; ldout = 2048; bx = u & 15; by = u >> 4;
  } else if (blk < 14336) {
    const int u = blk - 13312;
    in = Wv; out = WqkvT + (size_t)2560 * 2048; ldin = 512; ldout = 2048; bx = u & 15; by = u >> 4;
  } else {
    const int u = blk - 14336;
    in = Wo; out = WoT; ldin = 2048; ldout = 2048; bx = u & 63; by = u >> 6;
  }
  const int c0 = bx * 32, r0 = by * 32;
  const int tx = threadIdx.x & 31, ty = threadIdx.x >> 5;
#pragma unroll
  for (int j = 0; j < 4; ++j)
    tile[ty + j * 8][tx] = in[(size_t)(r0 + ty + j * 8) * ldin + c0 + tx];
  __syncthreads();
#pragma unroll
  for (int j = 0; j < 4; ++j)
    out[(size_t)(c0 + ty + j * 8) * ldout + r0 + tx] = f2bf(tile[tx][ty + j * 8]);
}

// ---------------- V slice of QKV -> VT [b*4+kv][128][2048] ----------------
__global__ void tr_v(const us* __restrict__ QKV, us* __restrict__ VT) {
  __shared__ us tile[32][33];
  const int z = blockIdx.z, b = z >> 2, kvh = z & 3;
  const us* in = QKV + (size_t)(b * 2048) * 3072 + 2560 + kvh * 128;
  us* out = VT + (size_t)z * 128 * 2048;
  const int c0 = blockIdx.x * 32, r0 = blockIdx.y * 32;
  const int tx = threadIdx.x, ty = threadIdx.y;
#pragma unroll
  for (int j = 0; j < 4; ++j)
    tile[ty + j * 8][tx] = in[(size_t)(r0 + ty + j * 8) * 3072 + c0 + tx];
  __syncthreads();
#pragma unroll
  for (int j = 0; j < 4; ++j)
    out[(size_t)(c0 + ty + j * 8) * 2048 + r0 + tx] = tile[tx][ty + j * 8];
}

// ---------------- bf16 GEMM 256x(64*NF), 2-phase/K-tile, counted vmcnt + XCD swizzle ----------------
template <int NF, int OUTF32>
__global__ __launch_bounds__(512, 2) void gemm256(const us* __restrict__ A,
                                                  const us* __restrict__ B,
                                                  void* __restrict__ Cv, int M, int N, int K) {
  __shared__ __attribute__((aligned(16))) us Ah[2][2][256 * 32];
  __shared__ __attribute__((aligned(16))) us Bf[2][64 * NF * 64];
  const int tid = threadIdx.x;
  const int lane = tid & 63;
  const int cl = lane & 15, rg = lane >> 4;
  const int wave = tid >> 6;
  const int wm = wave >> 2, wn = wave & 3;
  // XCD-aware bijective swizzle (nwg % 8 == 0): each XCD gets a contiguous chunk.
  const int nwg = gridDim.x * gridDim.y;
  const int bid = blockIdx.x + gridDim.x * blockIdx.y;
  const int swz = (bid & 7) * (nwg >> 3) + (bid >> 3);
  const int bn = swz % gridDim.x, bm = swz / gridDim.x;
  const int NK = K >> 6;
  const int rowA = bm * 256, rowB = bn * (64 * NF);

  f32x4 acc[8][NF] = {};

  auto stage_A = [&](int bf, int h, int kt) {
#pragma unroll
    for (int i = 0; i < 2; ++i) {
      const int L = i * 512 + tid;
      const int r = L >> 2;
      const int c = (L & 3) ^ ((r >> 1) & 3);
      load_lds16(A + (size_t)(rowA + r) * K + kt * 64 + h * 32 + c * 8,
                 &Ah[bf][h][(size_t)(i * 512 + (tid & ~63)) * 8]);
    }
  };
  auto stage_B = [&](int bf, int kt) {
#pragma unroll
    for (int i = 0; i < NF; ++i) {
      const int L = i * 512 + tid;
      const int r = L >> 3;
      const int c = (L & 7) ^ (r & 7);
      load_lds16(B + (size_t)(rowB + r) * K + kt * 64 + c * 8,
                 &Bf[bf][(size_t)(i * 512 + (tid & ~63)) * 8]);
    }
  };

  // prologue: B(NF), A-h0(2), A-h1(2); drain B+A0, keep A1 in flight
  stage_B(0, 0);
  stage_A(0, 0, 0);
  stage_A(0, 1, 0);
  asm volatile("s_waitcnt vmcnt(2)" ::: "memory");
  __builtin_amdgcn_s_barrier();

  int buf = 0;
#pragma unroll 1
  for (int kt = 0; kt < NK; ++kt) {
    const bool nl = (kt + 1 < NK);
    bf16x8 af[8], bfr[NF];

    // ---- PH0: kk = 0 ----
#pragma unroll
    for (int f = 0; f < 8; ++f) {
      const int r = 128 * wm + 16 * f + cl;
      af[f] = *(const bf16x8*)(&Ah[buf][0][(r * 4 + (rg ^ ((r >> 1) & 3))) * 8]);
    }
#pragma unroll
    for (int nf = 0; nf < NF; ++nf) {
      const int r = 16 * NF * wn + 16 * nf + cl;
      bfr[nf] = *(const bf16x8*)(&Bf[buf][(r * 8 + (rg ^ (r & 7))) * 8]);
    }
    if (nl) stage_B(buf ^ 1, kt + 1);
    __builtin_amdgcn_s_barrier();
    asm volatile("s_waitcnt lgkmcnt(0)" ::: "memory");
    __builtin_amdgcn_s_setprio(1);
#pragma unroll
    for (int f = 0; f < 8; ++f)
#pragma unroll
      for (int nf = 0; nf < NF; ++nf)
        acc[f][nf] = __builtin_amdgcn_mfma_f32_16x16x32_bf16(af[f], bfr[nf], acc[f][nf], 0, 0, 0);
    __builtin_amdgcn_s_setprio(0);
    if (nl) {
      if constexpr (NF == 3) { asm volatile("s_waitcnt vmcnt(3)" ::: "memory"); }
      else                   { asm volatile("s_waitcnt vmcnt(2)" ::: "memory"); }
    } else {
      asm volatile("s_waitcnt vmcnt(0)" ::: "memory");
    }
    __builtin_amdgcn_s_barrier();

    // ---- PH1: kk = 1 ----
#pragma unroll
    for (int f = 0; f < 8; ++f) {
      const int r = 128 * wm + 16 * f + cl;
      af[f] = *(const bf16x8*)(&Ah[buf][1][(r * 4 + (rg ^ ((r >> 1) & 3))) * 8]);
    }
#pragma unroll
    for (int nf = 0; nf < NF; ++nf) {
      const int r = 16 * NF * wn + 16 * nf + cl;
      bfr[nf] = *(const bf16x8*)(&Bf[buf][(r * 8 + ((4 + rg) ^ (r & 7))) * 8]);
    }
    if (nl) { stage_A(buf ^ 1, 0, kt + 1); stage_A(buf ^ 1, 1, kt + 1); }
    __builtin_amdgcn_s_barrier();
    asm volatile("s_waitcnt lgkmcnt(0)" ::: "memory");
    __builtin_amdgcn_s_setprio(1);
#pragma unroll
    for (int f = 0; f < 8; ++f)
#pragma unroll
      for (int nf = 0; nf < NF; ++nf)
        acc[f][nf] = __builtin_amdgcn_mfma_f32_16x16x32_bf16(af[f], bfr[nf], acc[f][nf], 0, 0, 0);
    __builtin_amdgcn_s_setprio(0);
    if (nl) asm volatile("s_waitcnt vmcnt(2)" ::: "memory");
    __builtin_amdgcn_s_barrier();

    buf ^= 1;
  }

#pragma unroll
  for (int f = 0; f < 8; ++f)
#pragma unroll
    for (int nf = 0; nf < NF; ++nf)
#pragma unroll
      for (int i = 0; i < 4; ++i) {
        const int row = bm * 256 + wm * 128 + f * 16 + rg * 4 + i;
        const int col = bn * 64 * NF + wn * 16 * NF + nf * 16 + cl;
        if (OUTF32)
          ((float*)Cv)[(size_t)row * N + col] = acc[f][nf][i];
        else
          ((us*)Cv)[(size_t)row * N + col] = f2bf(acc[f][nf][i]);
      }
}

// ---------------- causal GQA flash attention (round-5 version: measured best, 76 us) ----------------
__global__ __launch_bounds__(256, 2) void attn(const us* __restrict__ QKV,
                                               const us* __restrict__ VT,
                                               us* __restrict__ O) {
  __shared__ __attribute__((aligned(16))) us Ks[2][64 * 128];
  __shared__ __attribute__((aligned(16))) us VTs[2][128 * 64];
  const int T = 2048, LD = 3072, D = 2048;
  const int jp = blockIdx.x, h = blockIdx.y, b = blockIdx.z;
  const int kvh = h >> 2;
  const int tid = threadIdx.x, lane = tid & 63, wave = tid >> 6;
  const int cl = lane & 15, rg = lane >> 4;
  const bool abit = (lane & 16) != 0, bbit = (lane & 32) != 0;
  const bool ab = abit != bbit;
  const us* Kbase = QKV + (size_t)b * T * LD + 2048 + kvh * 128;
  const us* Vbase = VT + (size_t)(b * 4 + kvh) * 128 * T;

  auto stage = [&](int sb, int k0) {
#pragma unroll
    for (int i = 0; i < 4; ++i) {
      const int Ls = i * 256 + tid;
      const int r = Ls >> 4, s = Ls & 15, c = s ^ (r & 7);
      load_lds16(Kbase + (size_t)(k0 + r) * LD + c * 8,
                 &Ks[sb][(i * 256 + (tid & 0xC0)) * 8]);
    }
#pragma unroll
    for (int i = 0; i < 4; ++i) {
      const int Ls = i * 256 + tid;
      const int r = Ls >> 3, s = Ls & 7, c = s ^ (r & 7);
      load_lds16(Vbase + (size_t)r * T + k0 + c * 8,
                 &VTs[sb][(i * 256 + (tid & 0xC0)) * 8]);
    }
  };

  const float scale = 0.08838834764831845f;  // 1/sqrt(128)

#pragma unroll 1
  for (int pass = 0; pass < 2; ++pass) {
    const int jt = pass ? (31 - jp) : jp;
    const int q0 = jt * 64;
    const int nkt = jt + 1;
    const int qrow = q0 + wave * 16 + cl;

    const us* Qp = QKV + (size_t)(b * T + qrow) * LD + h * 128;
    bf16x8 qf[4];
#pragma unroll
    for (int ks = 0; ks < 4; ++ks) qf[ks] = *(const bf16x8*)(Qp + ks * 32 + rg * 8);

    f32x4 o[8] = {};
    float m = -1e30f, l = 0.f;
    int buf = 0;

    stage(0, 0);
    __syncthreads();

#pragma unroll 1
    for (int kt = 0; kt < nkt; ++kt) {
      if (kt + 1 < nkt) stage(buf ^ 1, (kt + 1) * 64);

      f32x4 sa[4] = {};
      __builtin_amdgcn_s_setprio(1);
#pragma unroll
      for (int ks = 0; ks < 4; ++ks) {
#pragma unroll
        for (int n = 0; n < 4; ++n) {
          const int row = n * 16 + cl;
          const int p = (ks * 4 + rg) ^ (row & 7);
          const bf16x8 kf = *(const bf16x8*)(&Ks[buf][row * 128 + p * 8]);
          sa[n] = __builtin_amdgcn_mfma_f32_16x16x32_bf16(kf, qf[ks], sa[n], 0, 0, 0);
        }
      }
      __builtin_amdgcn_s_setprio(0);

      const int k0 = kt * 64;
      float p[4][4];
      float pmax = -1e30f;
      if (kt == jt) {
#pragma unroll
        for (int n = 0; n < 4; ++n)
#pragma unroll
          for (int i = 0; i < 4; ++i) {
            const int kg = k0 + n * 16 + rg * 4 + i;
            p[n][i] = (kg > qrow) ? -1e30f : sa[n][i] * scale;
            pmax = fmaxf(pmax, p[n][i]);
          }
      } else {
#pragma unroll
        for (int n = 0; n < 4; ++n)
#pragma unroll
          for (int i = 0; i < 4; ++i) {
            p[n][i] = sa[n][i] * scale;
            pmax = fmaxf(pmax, p[n][i]);
          }
      }
      pmax = fmaxf(pmax, __shfl_xor(pmax, 16));
      pmax = fmaxf(pmax, __shfl_xor(pmax, 32));

      if (!__all(pmax <= m + 8.f)) {  // T13 defer-max
        const float mnew = fmaxf(m, pmax);
        const float alpha = __expf(m - mnew);
        m = mnew;
        l *= alpha;
#pragma unroll
        for (int n2 = 0; n2 < 8; ++n2) o[n2] *= alpha;
      }

      float rs = 0.f;
#pragma unroll
      for (int n = 0; n < 4; ++n)
#pragma unroll
        for (int i = 0; i < 4; ++i) {
          p[n][i] = __expf(p[n][i] - m);
          rs += p[n][i];
        }
      rs += __shfl_xor(rs, 16);
      rs += __shfl_xor(rs, 32);
      l += rs;

      unsigned int F[2][4];
#pragma unroll
      for (int ks2 = 0; ks2 < 2; ++ks2) {
        const unsigned int pk00 = pack2(p[2 * ks2][0], p[2 * ks2][1]);
        const unsigned int pk01 = pack2(p[2 * ks2][2], p[2 * ks2][3]);
        const unsigned int pk10 = pack2(p[2 * ks2 + 1][0], p[2 * ks2 + 1][1]);
        const unsigned int pk11 = pack2(p[2 * ks2 + 1][2], p[2 * ks2 + 1][3]);
        const unsigned int s0 = bbit ? pk00 : pk10;
        const unsigned int s1 = bbit ? pk01 : pk11;
        const unsigned int r0 = (unsigned int)__shfl_xor((int)s0, 32);
        const unsigned int r1 = (unsigned int)__shfl_xor((int)s1, 32);
        const unsigned int gk0 = bbit ? pk10 : pk00;
        const unsigned int gk1 = bbit ? pk11 : pk01;
        const unsigned int t0 = ab ? gk0 : r0;
        const unsigned int t1 = ab ? gk1 : r1;
        const unsigned int u0 = (unsigned int)__shfl_xor((int)t0, 16);
        const unsigned int u1 = (unsigned int)__shfl_xor((int)t1, 16);
        const unsigned int k20 = ab ? r0 : gk0;
        const unsigned int k21 = ab ? r1 : gk1;
        F[ks2][0] = abit ? u0 : k20;
        F[ks2][1] = abit ? u1 : k21;
        F[ks2][2] = abit ? k20 : u0;
        F[ks2][3] = abit ? k21 : u1;
      }

      __builtin_amdgcn_s_setprio(1);
#pragma unroll
      for (int ks2 = 0; ks2 < 2; ++ks2) {
        uint4 fu = make_uint4(F[ks2][0], F[ks2][1], F[ks2][2], F[ks2][3]);
        const bf16x8 pf = *(const bf16x8*)&fu;
#pragma unroll
        for (int n2 = 0; n2 < 8; ++n2) {
          const int dr = n2 * 16 + cl;
          const int p2 = (ks2 * 4 + rg) ^ (dr & 7);
          const bf16x8 vf = *(const bf16x8*)(&VTs[buf][dr * 64 + p2 * 8]);
          o[n2] = __builtin_amdgcn_mfma_f32_16x16x32_bf16(vf, pf, o[n2], 0, 0, 0);
        }
      }
      __builtin_amdgcn_s_setprio(0);

      __syncthreads();
      buf ^= 1;
    }

    const float rl = __builtin_amdgcn_rcpf(l);
#pragma unroll
    for (int n2 = 0; n2 < 8; ++n2) {
      ushort4 ov;
      ov.x = f2bf(o[n2][0] * rl);
      ov.y = f2bf(o[n2][1] * rl);
      ov.z = f2bf(o[n2][2] * rl);
      ov.w = f2bf(o[n2][3] * rl);
      *(ushort4*)(O + (size_t)(b * T + qrow) * D + h * 128 + n2 * 16 + rg * 4) = ov;
    }
  }
}

extern "C" void kernel_launch(void* const* d_in, const int* in_sizes, int n_in,
                              void* d_out, int out_size, void* d_ws, size_t ws_size,
                              hipStream_t stream) {
  const float* x = (const float*)d_in[0];
  const float* Wq = (const float*)d_in[1];
  const float* Wk = (const float*)d_in[2];
  const float* Wv = (const float*)d_in[3];
  const float* Wo = (const float*)d_in[4];
  float* out = (float*)d_out;

  char* ws = (char*)d_ws;
  us* xb    = (us*)(ws);                 // x bf16, later attn O
  us* WqkvT = (us*)(ws + 16777216);      // [3072][2048]
  us* WoT   = (us*)(ws + 29360128);      // [2048][2048]
  us* QKV   = (us*)(ws + 37748736);      // [4096][3072]
  us* VTb   = (us*)(ws + 62914560);      // [8][128][2048]

  prep<<<dim3(18432), dim3(256), 0, stream>>>(x, Wq, Wk, Wv, Wo, xb, WqkvT, WoT);
  gemm256<3, 0><<<dim3(16, 16), dim3(512), 0, stream>>>(xb, WqkvT, QKV, 4096, 3072, 2048);
  tr_v<<<dim3(4, 64, 8), dim3(32, 8), 0, stream>>>(QKV, VTb);
  attn<<<dim3(16, 16, 2), dim3(256), 0, stream>>>(QKV, VTb, xb);
  gemm256<2, 1><<<dim3(16, 16), dim3(512), 0, stream>>>(xb, WoT, out, 4096, 2048, 2048);
}